// Round 1
// baseline (322.287 us; speedup 1.0000x reference)
//
#include <hip/hip_runtime.h>
#include <hip/hip_bf16.h>

#define EPS 1e-10f
#define K_CLUST 50
#define C_DIM 32

// Kernel 1: one block computes the 50 cluster probabilities.
// Thread k (k < 50) runs the whole MLP for cluster k with hidden
// activations held in registers (loops fully unrolled, C=32).
__global__ __launch_bounds__(64) void cluster_probs_kernel(
    const float* __restrict__ emb,      // (K, C)
    const float* __restrict__ w1,       // (C, C)
    const float* __restrict__ b1,       // (C,)
    const float* __restrict__ w2,       // (C, C)
    const float* __restrict__ b2,       // (C,)
    const float* __restrict__ w3,       // (C, 1)
    const float* __restrict__ b3,       // (1,)
    const float* __restrict__ uniform,  // (2, K, 1) flat: [0..K) = u[0], [K..2K) = u[1]
    float* __restrict__ probs)          // (K,) output in workspace
{
    int k = threadIdx.x;
    if (k >= K_CLUST) return;

    // Layer 1: h1 = relu(emb[k] @ w1 + b1)
    float e[C_DIM];
#pragma unroll
    for (int c = 0; c < C_DIM; ++c) e[c] = emb[k * C_DIM + c];

    float h1[C_DIM];
#pragma unroll
    for (int j = 0; j < C_DIM; ++j) {
        float acc = b1[j];
#pragma unroll
        for (int c = 0; c < C_DIM; ++c) acc = fmaf(e[c], w1[c * C_DIM + j], acc);
        h1[j] = fmaxf(acc, 0.0f);
    }

    // Layer 2: h2 = relu(h1 @ w2 + b2)
    float h2[C_DIM];
#pragma unroll
    for (int j = 0; j < C_DIM; ++j) {
        float acc = b2[j];
#pragma unroll
        for (int c = 0; c < C_DIM; ++c) acc = fmaf(h1[c], w2[c * C_DIM + j], acc);
        h2[j] = fmaxf(acc, 0.0f);
    }

    // Layer 3: logit = h2 @ w3 + b3
    float logit = b3[0];
#pragma unroll
    for (int c = 0; c < C_DIM; ++c) logit = fmaf(h2[c], w3[c], logit);

    // Gumbel-ish noise: u = clip(uniform, EPS, 1-EPS);
    // noise = -log(log(u1)/log(u0) + EPS)
    float u0 = fminf(fmaxf(uniform[k], EPS), 1.0f - EPS);
    float u1 = fminf(fmaxf(uniform[K_CLUST + k], EPS), 1.0f - EPS);
    float noise = -logf(logf(u1) / logf(u0) + EPS);

    float z = logit + noise;
    probs[k] = 1.0f / (1.0f + expf(-z));
}

// Kernel 2: gather. Each thread handles 4 contiguous elements:
// int4 id load (16B/lane) + float4 store (16B/lane), probs table in LDS.
__global__ __launch_bounds__(256) void gather_kernel(
    const int* __restrict__ ids,
    const float* __restrict__ probs,
    float* __restrict__ out,
    int n4)  // number of 4-element groups
{
    __shared__ float s_probs[K_CLUST];
    int t = threadIdx.x;
    if (t < K_CLUST) s_probs[t] = probs[t];
    __syncthreads();

    int idx = blockIdx.x * 256 + t;
    if (idx >= n4) return;

    int4 id4 = ((const int4*)ids)[idx];
    float4 o;
    o.x = s_probs[id4.x];
    o.y = s_probs[id4.y];
    o.z = s_probs[id4.z];
    o.w = s_probs[id4.w];
    ((float4*)out)[idx] = o;
}

extern "C" void kernel_launch(void* const* d_in, const int* in_sizes, int n_in,
                              void* d_out, int out_size, void* d_ws, size_t ws_size,
                              hipStream_t stream) {
    // setup_inputs() order:
    // 0: feats (N,C) f32  -- UNUSED by reference
    // 1: cluster_ids (N,1) int
    // 2: emb (K,C) f32
    // 3: w1 (C,C) f32
    // 4: b1 (C,) f32
    // 5: w2 (C,C) f32
    // 6: b2 (C,) f32
    // 7: w3 (C,1) f32
    // 8: b3 (1,) f32
    // 9: uniform (2,K,1) f32
    const int*   ids     = (const int*)d_in[1];
    const float* emb     = (const float*)d_in[2];
    const float* w1      = (const float*)d_in[3];
    const float* b1      = (const float*)d_in[4];
    const float* w2      = (const float*)d_in[5];
    const float* b2      = (const float*)d_in[6];
    const float* w3      = (const float*)d_in[7];
    const float* b3      = (const float*)d_in[8];
    const float* uniform = (const float*)d_in[9];
    float*       out     = (float*)d_out;
    float*       probs   = (float*)d_ws;  // 50 floats of scratch

    int n = in_sizes[1];     // 2,000,000 (N*1)
    int n4 = n / 4;          // divisible by 4

    cluster_probs_kernel<<<1, 64, 0, stream>>>(emb, w1, b1, w2, b2, w3, b3,
                                               uniform, probs);

    int blocks = (n4 + 255) / 256;
    gather_kernel<<<blocks, 256, 0, stream>>>(ids, probs, out, n4);
}

// Round 3
// 322.049 us; speedup vs baseline: 1.0007x; 1.0007x over previous
//
#include <hip/hip_runtime.h>
#include <hip/hip_bf16.h>

#define EPS 1e-10f
#define K_CLUST 50
#define C_DIM 32

// Kernel 1: one block computes the 50 cluster probabilities.
// Thread k (k < 50) runs the whole MLP for cluster k with hidden
// activations held in registers (loops fully unrolled, C=32).
__global__ __launch_bounds__(64) void cluster_probs_kernel(
    const float* __restrict__ emb,      // (K, C)
    const float* __restrict__ w1,       // (C, C)
    const float* __restrict__ b1,       // (C,)
    const float* __restrict__ w2,       // (C, C)
    const float* __restrict__ b2,       // (C,)
    const float* __restrict__ w3,       // (C, 1)
    const float* __restrict__ b3,       // (1,)
    const float* __restrict__ uniform,  // (2, K, 1) flat: [0..K)=u[0], [K..2K)=u[1]
    float* __restrict__ probs)          // (K,) output in workspace
{
    int k = threadIdx.x;
    if (k >= K_CLUST) return;

    float e[C_DIM];
#pragma unroll
    for (int c = 0; c < C_DIM; ++c) e[c] = emb[k * C_DIM + c];

    float h1[C_DIM];
#pragma unroll
    for (int j = 0; j < C_DIM; ++j) {
        float acc = b1[j];
#pragma unroll
        for (int c = 0; c < C_DIM; ++c) acc = fmaf(e[c], w1[c * C_DIM + j], acc);
        h1[j] = fmaxf(acc, 0.0f);
    }

    float h2[C_DIM];
#pragma unroll
    for (int j = 0; j < C_DIM; ++j) {
        float acc = b2[j];
#pragma unroll
        for (int c = 0; c < C_DIM; ++c) acc = fmaf(h1[c], w2[c * C_DIM + j], acc);
        h2[j] = fmaxf(acc, 0.0f);
    }

    float logit = b3[0];
#pragma unroll
    for (int c = 0; c < C_DIM; ++c) logit = fmaf(h2[c], w3[c], logit);

    float u0 = fminf(fmaxf(uniform[k], EPS), 1.0f - EPS);
    float u1 = fminf(fmaxf(uniform[K_CLUST + k], EPS), 1.0f - EPS);
    float noise = -logf(logf(u1) / logf(u0) + EPS);

    float z = logit + noise;
    probs[k] = 1.0f / (1.0f + expf(-z));
}

// Gather from lane `id` of the per-lane probs register via the LDS crossbar.
// MUST be executed with all 64 lanes active: reads from inactive source
// lanes return undefined data (R2 bug).
__device__ __forceinline__ float bperm(float p, int id) {
    return __int_as_float(__builtin_amdgcn_ds_bpermute(id << 2, __float_as_int(p)));
}

// Kernel 2: gather, 8 elements per thread.
// Loads + bpermutes run with FULL exec (indices clamped in-bounds);
// only the stores are predicated — exec divergence there is harmless.
__global__ __launch_bounds__(256) void gather_kernel(
    const int* __restrict__ ids,
    const float* __restrict__ probs,
    float* __restrict__ out,
    int n4)  // number of 4-element groups
{
    int lane = threadIdx.x & 63;
    // lanes 50..63 hold a duplicate of probs[49]; never selected (ids < 50)
    float p = probs[lane < K_CLUST ? lane : (K_CLUST - 1)];

    const int4* ids4 = (const int4*)ids;
    float4* out4 = (float4*)out;

    int t = threadIdx.x;
    int g0 = blockIdx.x * 512 + t;   // first int4 group
    int g1 = g0 + 256;               // second int4 group (still coalesced)
    int c0 = min(g0, n4 - 1);        // clamped: always a valid load
    int c1 = min(g1, n4 - 1);

    int4 a = ids4[c0];
    int4 b = ids4[c1];

    float4 o0, o1;
    o0.x = bperm(p, a.x);
    o0.y = bperm(p, a.y);
    o0.z = bperm(p, a.z);
    o0.w = bperm(p, a.w);
    o1.x = bperm(p, b.x);
    o1.y = bperm(p, b.y);
    o1.z = bperm(p, b.z);
    o1.w = bperm(p, b.w);

    if (g0 < n4) out4[g0] = o0;
    if (g1 < n4) out4[g1] = o1;
}

extern "C" void kernel_launch(void* const* d_in, const int* in_sizes, int n_in,
                              void* d_out, int out_size, void* d_ws, size_t ws_size,
                              hipStream_t stream) {
    // setup_inputs() order:
    // 0: feats (N,C) f32  -- UNUSED by reference
    // 1: cluster_ids (N,1) int
    // 2: emb (K,C) f32
    // 3: w1 (C,C) f32
    // 4: b1 (C,) f32
    // 5: w2 (C,C) f32
    // 6: b2 (C,) f32
    // 7: w3 (C,1) f32
    // 8: b3 (1,) f32
    // 9: uniform (2,K,1) f32
    const int*   ids     = (const int*)d_in[1];
    const float* emb     = (const float*)d_in[2];
    const float* w1      = (const float*)d_in[3];
    const float* b1      = (const float*)d_in[4];
    const float* w2      = (const float*)d_in[5];
    const float* b2      = (const float*)d_in[6];
    const float* w3      = (const float*)d_in[7];
    const float* b3      = (const float*)d_in[8];
    const float* uniform = (const float*)d_in[9];
    float*       out     = (float*)d_out;
    float*       probs   = (float*)d_ws;  // 50 floats of scratch

    int n = in_sizes[1];     // 2,000,000
    int n4 = n / 4;          // 500,000 int4 groups

    cluster_probs_kernel<<<1, 64, 0, stream>>>(emb, w1, b1, w2, b2, w3, b3,
                                               uniform, probs);

    // 512 groups per block of 256 threads (8 elements/thread)
    int blocks = (n4 + 511) / 512;   // 977
    gather_kernel<<<blocks, 256, 0, stream>>>(ids, probs, out, n4);
}